// Round 3
// baseline (487.013 us; speedup 1.0000x reference)
//
#include <hip/hip_runtime.h>
#include <cstdint>

// Problem constants (from reference file)
constexpr int Bb = 8;     // batch
constexpr int Cc = 256;   // channels
constexpr int Tt = 1024;  // time
constexpr int Mm = 512;   // num_masked
constexpr int Kk = 100;   // negatives per position
#define EPSF 1e-8f
#define INV_TEMP 10.0f

// ---------------------------------------------------------------------------
// Single fused kernel. grid = Bb*Mm (=4096) blocks, 256 threads (4 waves).
// Per block (b = bm>>9, m = bm&511):
//   Phase 0: mask element-width auto-detect (1/4/8B) on first 1024 elements
//            (exactly Mm nonzero bytes in first 1024 bytes <=> 1-byte layout;
//             int32/int64 layouts can put at most 256/128 set entries there).
//   Phase 1: in-block prefix-scan over mask row b -> t = m-th set position.
//   Phase 2: gather ctx/pos column t, block-reduce norms/dot.
//   Phase 3: stream this bm's 100x256 negatives (contiguous 102.4 KB),
//            16 k per iter (4 waves x 4 sub-k of 16 lanes), raw logits.
//   Phase 4: wave-0 logsumexp (shared scale 10/||ctx|| applied here).
//   Phase 5: last-block-done fixed-order mean reduce (deterministic).
// All prologue phases are L3-hot and overlap other resident blocks' streams.
// ---------------------------------------------------------------------------
__global__ __launch_bounds__(256)
void cl_fused(const float* __restrict__ context,
              const float* __restrict__ positive,
              const float* __restrict__ negatives,
              const void*  __restrict__ mask,
              float* __restrict__ lossbuf,
              int*   __restrict__ done_cnt,
              float* __restrict__ out) {
    const int bm   = blockIdx.x;           // 0..4095
    const int b    = bm >> 9;
    const int m    = bm & (Mm - 1);
    const int tid  = threadIdx.x;          // 0..255
    const int lane = tid & 63;
    const int wave = tid >> 6;             // 0..3
    const int q    = lane & 15;
    const int ks   = lane >> 4;            // 0..3

    __shared__ __align__(16) float ctx_s[Cc];
    __shared__ float redf[4][3];
    __shared__ int   redi[4][2];
    __shared__ int   scan_w[4];
    __shared__ float logits[Kk + 1];
    __shared__ int   t_s;
    __shared__ int   last_flag;

    const uint8_t* p8  = (const uint8_t*)mask;
    const int32_t* p32 = (const int32_t*)mask;

    // ---- Phase 0: layout detection (first 1024 bytes / first 1024 ints) ----
    int c8 = 0, c32 = 0;
    #pragma unroll
    for (int j = 0; j < 4; ++j) {
        c8  += (p8 [j * 256 + tid] != 0);
        c32 += (p32[j * 256 + tid] != 0);
    }
    #pragma unroll
    for (int d = 32; d >= 1; d >>= 1) { c8 += __shfl_xor(c8, d); c32 += __shfl_xor(c32, d); }
    if (lane == 0) { redi[wave][0] = c8; redi[wave][1] = c32; }
    __syncthreads();
    const int tc8  = redi[0][0] + redi[1][0] + redi[2][0] + redi[3][0];
    const int tc32 = redi[0][1] + redi[1][1] + redi[2][1] + redi[3][1];
    const int esz  = (tc8 == Mm) ? 1 : ((tc32 == Mm) ? 4 : 8);

    // ---- Phase 1: find t = position of (m+1)-th set bit in mask row b ----
    // thread tid owns elements [tid*4, tid*4+4) of the row
    int bits = 0;
    if (esz == 1) {
        const uint32_t w = *(const uint32_t*)(p8 + (size_t)b * Tt + tid * 4);
        bits = ((w & 0xffu)       ? 1 : 0) |
               ((w & 0xff00u)     ? 2 : 0) |
               ((w & 0xff0000u)   ? 4 : 0) |
               ((w & 0xff000000u) ? 8 : 0);
    } else if (esz == 4) {
        #pragma unroll
        for (int j = 0; j < 4; ++j)
            bits |= (p32[(size_t)b * Tt + tid * 4 + j] != 0) << j;
    } else {
        const int64_t* p64 = (const int64_t*)mask;
        #pragma unroll
        for (int j = 0; j < 4; ++j)
            bits |= (p64[(size_t)b * Tt + tid * 4 + j] != 0) << j;
    }
    const int cnt = __popc(bits);
    int incl = cnt;
    #pragma unroll
    for (int d = 1; d < 64; d <<= 1) { const int v = __shfl_up(incl, d); if (lane >= d) incl += v; }
    if (lane == 63) scan_w[wave] = incl;
    __syncthreads();
    int base = 0;
    for (int w = 0; w < wave; ++w) base += scan_w[w];
    incl += base;
    const int excl = incl - cnt;
    if (excl <= m && m < incl) {
        int need = m - excl;
        #pragma unroll
        for (int j = 0; j < 4; ++j) {
            if ((bits >> j) & 1) { if (need == 0) t_s = tid * 4 + j; --need; }
        }
    }
    __syncthreads();
    const int t = t_s;

    // ---- Phase 2: gather columns + block reduce norms/dot ----
    const float cv = context [((size_t)(b * Cc + tid)) * Tt + t];
    const float pv = positive[((size_t)(b * Cc + tid)) * Tt + t];
    ctx_s[tid] = cv;
    float s0 = cv * cv, s1 = pv * pv, s2 = cv * pv;
    #pragma unroll
    for (int d = 32; d >= 1; d >>= 1) {
        s0 += __shfl_xor(s0, d);
        s1 += __shfl_xor(s1, d);
        s2 += __shfl_xor(s2, d);
    }
    if (lane == 0) { redf[wave][0] = s0; redf[wave][1] = s1; redf[wave][2] = s2; }
    __syncthreads();

    // each lane's 16 raw ctx values -> registers (c = j*64 + q*4 + i)
    const float4* c4 = (const float4*)ctx_s;
    float4 cr[4];
    #pragma unroll
    for (int j = 0; j < 4; ++j) cr[j] = c4[j * 16 + q];

    // ---- Phase 3: negatives stream, 16 k per iteration ----
    const long long nbase = (long long)bm * Kk * Cc;
    #pragma unroll 2
    for (int it = 0; it < 7; ++it) {
        const int k = it * 16 + wave * 4 + ks;
        float dotp = 0.f, sq = 0.f;
        if (k < Kk) {
            const float4* np4 = (const float4*)(negatives + nbase + (long long)k * Cc);
            #pragma unroll
            for (int j = 0; j < 4; ++j) {
                const float4 nv = np4[j * 16 + q];
                dotp += cr[j].x * nv.x + cr[j].y * nv.y + cr[j].z * nv.z + cr[j].w * nv.w;
                sq   += nv.x * nv.x + nv.y * nv.y + nv.z * nv.z + nv.w * nv.w;
            }
        }
        #pragma unroll
        for (int d = 1; d <= 8; d <<= 1) {
            dotp += __shfl_xor(dotp, d);
            sq   += __shfl_xor(sq, d);
        }
        if (k < Kk && q == 0) {
            const float nb = fmaxf(sqrtf(sq), EPSF);
            logits[1 + k] = dotp / nb;   // raw: missing 10/||ctx||
        }
    }
    __syncthreads();

    // ---- Phase 4: wave-0 logsumexp over 101 logits ----
    if (wave == 0) {
        const float na2 = redf[0][0] + redf[1][0] + redf[2][0] + redf[3][0];
        const float np2 = redf[0][1] + redf[1][1] + redf[2][1] + redf[3][1];
        const float dcp = redf[0][2] + redf[1][2] + redf[2][2] + redf[3][2];
        const float na = fmaxf(sqrtf(na2), EPSF);
        const float np = fmaxf(sqrtf(np2), EPSF);
        const float scale = INV_TEMP / na;

        const float a_raw = (lane == 0) ? (dcp / np) : logits[lane];
        const float b_raw = (lane + 64 <= Kk) ? logits[lane + 64] : -3e28f;
        const float a  = a_raw * scale;
        const float bb = b_raw * scale;

        float mx = fmaxf(a, bb);
        #pragma unroll
        for (int d = 32; d >= 1; d >>= 1) mx = fmaxf(mx, __shfl_xor(mx, d));
        float e = expf(a - mx) + expf(bb - mx);
        #pragma unroll
        for (int d = 32; d >= 1; d >>= 1) e += __shfl_xor(e, d);
        const float logit0 = __shfl(a, 0);
        if (lane == 0) lossbuf[bm] = mx + logf(e) - logit0;
    }

    // ---- Phase 5: last-block fixed-order mean reduce ----
    if (tid == 0) {
        __threadfence();   // release lossbuf[bm] (written by this same thread)
        const int old = __hip_atomic_fetch_add(done_cnt, 1, __ATOMIC_ACQ_REL,
                                               __HIP_MEMORY_SCOPE_AGENT);
        last_flag = (old == (int)gridDim.x - 1);
    }
    __syncthreads();
    if (last_flag) {
        float s = 0.f;
        #pragma unroll
        for (int i = 0; i < 16; ++i)
            s += __hip_atomic_load(&lossbuf[tid * 16 + i], __ATOMIC_RELAXED,
                                   __HIP_MEMORY_SCOPE_AGENT);
        #pragma unroll
        for (int d = 32; d >= 1; d >>= 1) s += __shfl_xor(s, d);
        if (lane == 0) redf[wave][0] = s;
        __syncthreads();
        if (tid == 0)
            out[0] = (redf[0][0] + redf[1][0] + redf[2][0] + redf[3][0]) * (1.0f / (Bb * Mm));
    }
}

extern "C" void kernel_launch(void* const* d_in, const int* in_sizes, int n_in,
                              void* d_out, int out_size, void* d_ws, size_t ws_size,
                              hipStream_t stream) {
    const float* context   = (const float*)d_in[0];
    const float* positive  = (const float*)d_in[1];
    const float* negatives = (const float*)d_in[2];
    const void*  mask      = d_in[3];
    // d_in[4] = num_masked (512) — hardcoded as Mm.

    float* lossbuf  = (float*)d_ws;                         // 16 KB
    int*   done_cnt = (int*)((char*)d_ws + Bb * Mm * sizeof(float));

    hipMemsetAsync(done_cnt, 0, sizeof(int), stream);
    cl_fused<<<Bb * Mm, 256, 0, stream>>>(context, positive, negatives, mask,
                                          lossbuf, done_cnt, (float*)d_out);
}

// Round 5
// 93.990 us; speedup vs baseline: 5.1816x; 5.1816x over previous
//
#include <hip/hip_runtime.h>
#include <cstdint>

// Problem constants (from reference file)
constexpr int Bb = 8;     // batch
constexpr int Cc = 256;   // channels
constexpr int Tt = 1024;  // time
constexpr int Mm = 512;   // num_masked
constexpr int Kk = 100;   // negatives per position
constexpr int PAIRS = 2;  // bm's per block (2-deep pipeline)
constexpr int GRID  = (Bb * Mm) / PAIRS;   // 2048
#define EPSF 1e-8f
#define INV_TEMP 10.0f

typedef float vf4 __attribute__((ext_vector_type(4)));  // clang vector: ok for nontemporal builtin

// ---------------------------------------------------------------------------
// Kernel A: extract masked indices per batch row, ascending t order.
// (unchanged from R1 — verified absmax 0.0)
// ---------------------------------------------------------------------------
__global__ __launch_bounds__(1024)
void cl_mask_extract(const void* __restrict__ mask, int* __restrict__ idx) {
    const int b    = blockIdx.x;
    const int tid  = threadIdx.x;          // 0..1023
    const int lane = tid & 63;
    const int wave = tid >> 6;             // 0..15

    __shared__ int wcnt8[16];
    __shared__ int wcnt32[16];
    __shared__ int wcntp[16];
    __shared__ int layout_s;

    const uint8_t* p8  = (const uint8_t*)mask;
    const int32_t* p32 = (const int32_t*)mask;
    unsigned long long bal8  = __ballot(p8[tid]  != 0);
    unsigned long long bal32 = __ballot(p32[tid] != 0);
    if (lane == 0) { wcnt8[wave] = __popcll(bal8); wcnt32[wave] = __popcll(bal32); }
    __syncthreads();
    if (tid == 0) {
        int c8 = 0, c32 = 0;
        for (int w = 0; w < 16; ++w) { c8 += wcnt8[w]; c32 += wcnt32[w]; }
        layout_s = (c8 == Mm) ? 1 : ((c32 == Mm) ? 4 : 8);
    }
    __syncthreads();
    const int esz = layout_s;

    const long long off = (long long)b * Tt + tid;
    int bit;
    if (esz == 1)      bit = (p8[off]  != 0);
    else if (esz == 4) bit = (p32[off] != 0);
    else               bit = (((const int64_t*)mask)[off] != 0);

    unsigned long long bp = __ballot(bit);
    if (lane == 0) wcntp[wave] = __popcll(bp);
    __syncthreads();
    int base = 0;
    for (int w = 0; w < wave; ++w) base += wcntp[w];
    const int rank = base + __popcll(bp & ((1ull << lane) - 1ull));
    if (bit && rank < Mm) idx[b * Mm + rank] = tid;
}

// ---------------------------------------------------------------------------
// Kernel B: per-(b,m) cosine logits + logsumexp, 2-deep pipelined.
// grid = 2048 blocks, 256 threads (4 waves). Block g handles bm0=g, bm1=g+2048.
// All 4 gather loads issue at the top (latency overlapped once); both norm
// reductions done before streaming; bm1's stream follows bm0's with no
// exposed prologue. Wave 0's LSE for bm0 overlaps waves 1-3 starting bm1.
// Negatives use non-temporal loads (stream-once data, keep caches for
// ctx/pos/idx).
// ---------------------------------------------------------------------------
__global__ __launch_bounds__(256)
void cl_main(const float* __restrict__ context,
             const float* __restrict__ positive,
             const float* __restrict__ negatives,
             const int*   __restrict__ idx,
             float*       __restrict__ lossbuf) {
    const int g    = blockIdx.x;           // 0..2047
    const int bm0  = g;
    const int bm1  = g + GRID;
    const int b0   = bm0 >> 9;
    const int b1   = bm1 >> 9;
    const int tid  = threadIdx.x;          // 0..255
    const int lane = tid & 63;
    const int wave = tid >> 6;             // 0..3
    const int q    = lane & 15;
    const int ks   = lane >> 4;            // 0..3

    __shared__ __align__(16) float ctx_s[2][Cc];
    __shared__ float redf[4][6];
    __shared__ float logits[2][Kk + 4];

    // ---- issue all gathers up front ----
    const int t0 = idx[bm0];
    const int t1 = idx[bm1];
    const float cv0 = context [((size_t)(b0 * Cc + tid)) * Tt + t0];
    const float pv0 = positive[((size_t)(b0 * Cc + tid)) * Tt + t0];
    const float cv1 = context [((size_t)(b1 * Cc + tid)) * Tt + t1];
    const float pv1 = positive[((size_t)(b1 * Cc + tid)) * Tt + t1];
    ctx_s[0][tid] = cv0;
    ctx_s[1][tid] = cv1;

    // ---- both norm/dot reductions ----
    float s0 = cv0 * cv0, s1 = pv0 * pv0, s2 = cv0 * pv0;
    float s3 = cv1 * cv1, s4 = pv1 * pv1, s5 = cv1 * pv1;
    #pragma unroll
    for (int d = 32; d >= 1; d >>= 1) {
        s0 += __shfl_xor(s0, d); s1 += __shfl_xor(s1, d); s2 += __shfl_xor(s2, d);
        s3 += __shfl_xor(s3, d); s4 += __shfl_xor(s4, d); s5 += __shfl_xor(s5, d);
    }
    if (lane == 0) {
        redf[wave][0] = s0; redf[wave][1] = s1; redf[wave][2] = s2;
        redf[wave][3] = s3; redf[wave][4] = s4; redf[wave][5] = s5;
    }
    __syncthreads();

    // ---- ctx fragments for both bm's -> registers (c = j*64 + q*4 + i) ----
    const float4* c40 = (const float4*)ctx_s[0];
    const float4* c41 = (const float4*)ctx_s[1];
    float4 cr0[4], cr1[4];
    #pragma unroll
    for (int j = 0; j < 4; ++j) { cr0[j] = c40[j * 16 + q]; cr1[j] = c41[j * 16 + q]; }

    // ---- streaming k-loop ----
    auto kloop = [&](const float4* cr, long long nbase, float* lrow) {
        #pragma unroll 2
        for (int it = 0; it < 7; ++it) {
            const int k = it * 16 + wave * 4 + ks;
            float dotp = 0.f, sq = 0.f;
            if (k < Kk) {
                const vf4* np4 = (const vf4*)(negatives + nbase + (long long)k * Cc);
                #pragma unroll
                for (int j = 0; j < 4; ++j) {
                    const vf4 nv = __builtin_nontemporal_load(np4 + j * 16 + q);
                    dotp += cr[j].x * nv.x + cr[j].y * nv.y + cr[j].z * nv.z + cr[j].w * nv.w;
                    sq   += nv.x * nv.x + nv.y * nv.y + nv.z * nv.z + nv.w * nv.w;
                }
            }
            #pragma unroll
            for (int d = 1; d <= 8; d <<= 1) {
                dotp += __shfl_xor(dotp, d);
                sq   += __shfl_xor(sq, d);
            }
            if (k < Kk && q == 0) {
                const float nb = fmaxf(sqrtf(sq), EPSF);
                lrow[1 + k] = dotp / nb;     // raw: missing 10/||ctx||
            }
        }
    };

    // ---- LSE over 101 logits (wave 0 only) ----
    auto lse = [&](const float* lrow, float na2, float np2, float dcp, int bm) {
        const float na = fmaxf(sqrtf(na2), EPSF);
        const float np = fmaxf(sqrtf(np2), EPSF);
        const float scale = INV_TEMP / na;
        const float a_raw = (lane == 0) ? (dcp / np) : lrow[lane];
        const float b_raw = (lane + 64 <= Kk) ? lrow[lane + 64] : -3e28f;
        const float a  = a_raw * scale;
        const float bb = b_raw * scale;
        float mx = fmaxf(a, bb);
        #pragma unroll
        for (int d = 32; d >= 1; d >>= 1) mx = fmaxf(mx, __shfl_xor(mx, d));
        float e = expf(a - mx) + expf(bb - mx);
        #pragma unroll
        for (int d = 32; d >= 1; d >>= 1) e += __shfl_xor(e, d);
        const float logit0 = __shfl(a, 0);
        if (lane == 0) lossbuf[bm] = mx + logf(e) - logit0;
    };

    // ---- bm0 stream ----
    kloop(cr0, (long long)bm0 * Kk * Cc, logits[0]);
    __syncthreads();

    // ---- wave0: LSE(bm0); all waves: bm1 stream ----
    if (wave == 0) {
        const float na2 = redf[0][0] + redf[1][0] + redf[2][0] + redf[3][0];
        const float np2 = redf[0][1] + redf[1][1] + redf[2][1] + redf[3][1];
        const float dcp = redf[0][2] + redf[1][2] + redf[2][2] + redf[3][2];
        lse(logits[0], na2, np2, dcp, bm0);
    }
    kloop(cr1, (long long)bm1 * Kk * Cc, logits[1]);
    __syncthreads();

    if (wave == 0) {
        const float na2 = redf[0][3] + redf[1][3] + redf[2][3] + redf[3][3];
        const float np2 = redf[0][4] + redf[1][4] + redf[2][4] + redf[3][4];
        const float dcp = redf[0][5] + redf[1][5] + redf[2][5] + redf[3][5];
        lse(logits[1], na2, np2, dcp, bm1);
    }
}

// ---------------------------------------------------------------------------
// Kernel C: deterministic mean over 4096 per-(b,m) losses.
// ---------------------------------------------------------------------------
__global__ __launch_bounds__(256)
void cl_reduce(const float* __restrict__ lossbuf, float* __restrict__ out) {
    const int tid = threadIdx.x;   // 0..255
    float s = 0.f;
    #pragma unroll
    for (int i = 0; i < 16; ++i) s += lossbuf[tid * 16 + i];
    #pragma unroll
    for (int d = 32; d >= 1; d >>= 1) s += __shfl_xor(s, d);
    __shared__ float ws[4];
    if ((tid & 63) == 0) ws[tid >> 6] = s;
    __syncthreads();
    if (tid == 0) out[0] = (ws[0] + ws[1] + ws[2] + ws[3]) * (1.0f / (Bb * Mm));
}

extern "C" void kernel_launch(void* const* d_in, const int* in_sizes, int n_in,
                              void* d_out, int out_size, void* d_ws, size_t ws_size,
                              hipStream_t stream) {
    const float* context   = (const float*)d_in[0];
    const float* positive  = (const float*)d_in[1];
    const float* negatives = (const float*)d_in[2];
    const void*  mask      = d_in[3];
    // d_in[4] = num_masked (512) — hardcoded as Mm.

    int*   idx     = (int*)d_ws;                                    // 16 KB
    float* lossbuf = (float*)(idx + Bb * Mm);                       // 16 KB

    cl_mask_extract<<<Bb, 1024, 0, stream>>>(mask, idx);
    cl_main<<<GRID, 256, 0, stream>>>(context, positive, negatives, idx, lossbuf);
    cl_reduce<<<1, 256, 0, stream>>>(lossbuf, (float*)d_out);
}

// Round 6
// 90.685 us; speedup vs baseline: 5.3704x; 1.0364x over previous
//
#include <hip/hip_runtime.h>
#include <cstdint>

// Problem constants (from reference file)
constexpr int Bb = 8;     // batch
constexpr int Cc = 256;   // channels
constexpr int Tt = 1024;  // time
constexpr int Mm = 512;   // num_masked
constexpr int Kk = 100;   // negatives per position
constexpr int GRID = (Bb * Mm) / 2;   // 2048 blocks, 2 bm's each
#define EPSF 1e-8f
#define INV_TEMP 10.0f

typedef float vf4 __attribute__((ext_vector_type(4)));

// ---------------------------------------------------------------------------
// Fused main kernel. grid = 2048 blocks, 256 threads (4 waves).
// Block g handles bm0 = 2g and bm1 = 2g+1 — SAME mask row b = g>>8, so one
// in-block mask scan yields both t's, and the two 102.4 KB negative streams
// are adjacent in memory.
//   Phase 0: mask element-width auto-detect (1/4/8B) on first 1024 elements.
//   Phase 1: one prefix-scan of mask row b -> t0 (m0-th set bit), t1 (m0+1).
//   Phase 2: gather ctx/pos columns t0,t1; block-reduce norms/dots.
//   Phase 3: stream bm0's negatives; wave0 LSE(bm0) overlaps bm1's stream.
// No cross-block communication (atomics burned us in R3 — 5x regression).
// ---------------------------------------------------------------------------
__global__ __launch_bounds__(256)
void cl_main(const float* __restrict__ context,
             const float* __restrict__ positive,
             const float* __restrict__ negatives,
             const void*  __restrict__ mask,
             float*       __restrict__ lossbuf) {
    const int g    = blockIdx.x;           // 0..2047
    const int bm0  = g * 2;
    const int b    = bm0 >> 9;             // same row for bm0 and bm1
    const int m0   = bm0 & (Mm - 1);
    const int tid  = threadIdx.x;          // 0..255
    const int lane = tid & 63;
    const int wave = tid >> 6;             // 0..3
    const int q    = lane & 15;
    const int ks   = lane >> 4;            // 0..3

    __shared__ __align__(16) float ctx_s[2][Cc];
    __shared__ float redf[4][6];
    __shared__ int   redi[4][2];
    __shared__ int   scan_w[4];
    __shared__ float logits[2][Kk + 4];
    __shared__ int   t_sh[2];

    const uint8_t* p8  = (const uint8_t*)mask;
    const int32_t* p32 = (const int32_t*)mask;

    // ---- Phase 0: layout detection (first 1024 bytes / first 1024 ints) ----
    int c8 = 0, c32 = 0;
    #pragma unroll
    for (int j = 0; j < 4; ++j) {
        c8  += (p8 [j * 256 + tid] != 0);
        c32 += (p32[j * 256 + tid] != 0);
    }
    #pragma unroll
    for (int d = 32; d >= 1; d >>= 1) { c8 += __shfl_xor(c8, d); c32 += __shfl_xor(c32, d); }
    if (lane == 0) { redi[wave][0] = c8; redi[wave][1] = c32; }
    __syncthreads();
    const int tc8  = redi[0][0] + redi[1][0] + redi[2][0] + redi[3][0];
    const int tc32 = redi[0][1] + redi[1][1] + redi[2][1] + redi[3][1];
    const int esz  = (tc8 == Mm) ? 1 : ((tc32 == Mm) ? 4 : 8);

    // ---- Phase 1: prefix-scan mask row b; select m0-th and (m0+1)-th bits --
    int bits = 0;
    if (esz == 1) {
        const uint32_t w = *(const uint32_t*)(p8 + (size_t)b * Tt + tid * 4);
        bits = ((w & 0xffu)       ? 1 : 0) |
               ((w & 0xff00u)     ? 2 : 0) |
               ((w & 0xff0000u)   ? 4 : 0) |
               ((w & 0xff000000u) ? 8 : 0);
    } else if (esz == 4) {
        #pragma unroll
        for (int j = 0; j < 4; ++j)
            bits |= (p32[(size_t)b * Tt + tid * 4 + j] != 0) << j;
    } else {
        const int64_t* p64 = (const int64_t*)mask;
        #pragma unroll
        for (int j = 0; j < 4; ++j)
            bits |= (p64[(size_t)b * Tt + tid * 4 + j] != 0) << j;
    }
    const int cnt = __popc(bits);
    int incl = cnt;
    #pragma unroll
    for (int d = 1; d < 64; d <<= 1) { const int v = __shfl_up(incl, d); if (lane >= d) incl += v; }
    if (lane == 63) scan_w[wave] = incl;
    __syncthreads();
    int basec = 0;
    for (int w = 0; w < wave; ++w) basec += scan_w[w];
    incl += basec;
    const int excl = incl - cnt;
    #pragma unroll
    for (int sel = 0; sel < 2; ++sel) {
        const int mm = m0 + sel;
        if (excl <= mm && mm < incl) {
            int need = mm - excl;
            #pragma unroll
            for (int j = 0; j < 4; ++j) {
                if ((bits >> j) & 1) { if (need == 0) t_sh[sel] = tid * 4 + j; --need; }
            }
        }
    }
    __syncthreads();
    const int t0 = t_sh[0];
    const int t1 = t_sh[1];

    // ---- Phase 2: gather ctx/pos columns + block reduces ----
    const float* crow = context  + (size_t)(b * Cc + tid) * Tt;
    const float* prow = positive + (size_t)(b * Cc + tid) * Tt;
    const float cv0 = crow[t0];
    const float pv0 = prow[t0];
    const float cv1 = crow[t1];
    const float pv1 = prow[t1];
    ctx_s[0][tid] = cv0;
    ctx_s[1][tid] = cv1;

    float s0 = cv0 * cv0, s1 = pv0 * pv0, s2 = cv0 * pv0;
    float s3 = cv1 * cv1, s4 = pv1 * pv1, s5 = cv1 * pv1;
    #pragma unroll
    for (int d = 32; d >= 1; d >>= 1) {
        s0 += __shfl_xor(s0, d); s1 += __shfl_xor(s1, d); s2 += __shfl_xor(s2, d);
        s3 += __shfl_xor(s3, d); s4 += __shfl_xor(s4, d); s5 += __shfl_xor(s5, d);
    }
    if (lane == 0) {
        redf[wave][0] = s0; redf[wave][1] = s1; redf[wave][2] = s2;
        redf[wave][3] = s3; redf[wave][4] = s4; redf[wave][5] = s5;
    }
    __syncthreads();

    const float4* c40 = (const float4*)ctx_s[0];
    const float4* c41 = (const float4*)ctx_s[1];
    float4 cr0[4], cr1[4];
    #pragma unroll
    for (int j = 0; j < 4; ++j) { cr0[j] = c40[j * 16 + q]; cr1[j] = c41[j * 16 + q]; }

    // ---- streaming k-loop ----
    auto kloop = [&](const float4* cr, long long nbase, float* lrow) {
        #pragma unroll 2
        for (int it = 0; it < 7; ++it) {
            const int k = it * 16 + wave * 4 + ks;
            float dotp = 0.f, sq = 0.f;
            if (k < Kk) {
                const vf4* np4 = (const vf4*)(negatives + nbase + (long long)k * Cc);
                #pragma unroll
                for (int j = 0; j < 4; ++j) {
                    const vf4 nv = __builtin_nontemporal_load(np4 + j * 16 + q);
                    dotp += cr[j].x * nv.x + cr[j].y * nv.y + cr[j].z * nv.z + cr[j].w * nv.w;
                    sq   += nv.x * nv.x + nv.y * nv.y + nv.z * nv.z + nv.w * nv.w;
                }
            }
            #pragma unroll
            for (int d = 1; d <= 8; d <<= 1) {
                dotp += __shfl_xor(dotp, d);
                sq   += __shfl_xor(sq, d);
            }
            if (k < Kk && q == 0) {
                const float nb = fmaxf(sqrtf(sq), EPSF);
                lrow[1 + k] = dotp / nb;     // raw: missing 10/||ctx||
            }
        }
    };

    // ---- LSE over 101 logits (wave 0 only) ----
    auto lse = [&](const float* lrow, float na2, float np2, float dcp, int bm) {
        const float na = fmaxf(sqrtf(na2), EPSF);
        const float np = fmaxf(sqrtf(np2), EPSF);
        const float scale = INV_TEMP / na;
        const float a_raw = (lane == 0) ? (dcp / np) : lrow[lane];
        const float b_raw = (lane + 64 <= Kk) ? lrow[lane + 64] : -3e28f;
        const float a  = a_raw * scale;
        const float bb = b_raw * scale;
        float mx = fmaxf(a, bb);
        #pragma unroll
        for (int d = 32; d >= 1; d >>= 1) mx = fmaxf(mx, __shfl_xor(mx, d));
        float e = expf(a - mx) + expf(bb - mx);
        #pragma unroll
        for (int d = 32; d >= 1; d >>= 1) e += __shfl_xor(e, d);
        const float logit0 = __shfl(a, 0);
        if (lane == 0) lossbuf[bm] = mx + logf(e) - logit0;
    };

    const long long nbase0 = (long long)bm0 * Kk * Cc;

    // ---- bm0 stream ----
    kloop(cr0, nbase0, logits[0]);
    __syncthreads();

    // ---- wave0: LSE(bm0); all waves: bm1 stream ----
    if (wave == 0) {
        const float na2 = redf[0][0] + redf[1][0] + redf[2][0] + redf[3][0];
        const float np2 = redf[0][1] + redf[1][1] + redf[2][1] + redf[3][1];
        const float dcp = redf[0][2] + redf[1][2] + redf[2][2] + redf[3][2];
        lse(logits[0], na2, np2, dcp, bm0);
    }
    kloop(cr1, nbase0 + (long long)Kk * Cc, logits[1]);
    __syncthreads();

    if (wave == 0) {
        const float na2 = redf[0][3] + redf[1][3] + redf[2][3] + redf[3][3];
        const float np2 = redf[0][4] + redf[1][4] + redf[2][4] + redf[3][4];
        const float dcp = redf[0][5] + redf[1][5] + redf[2][5] + redf[3][5];
        lse(logits[1], na2, np2, dcp, bm0 + 1);
    }
}

// ---------------------------------------------------------------------------
// Deterministic mean over 4096 per-(b,m) losses.
// ---------------------------------------------------------------------------
__global__ __launch_bounds__(256)
void cl_reduce(const float* __restrict__ lossbuf, float* __restrict__ out) {
    const int tid = threadIdx.x;   // 0..255
    float s = 0.f;
    #pragma unroll
    for (int i = 0; i < 4; ++i) {
        const float4 v = *(const float4*)(lossbuf + tid * 16 + i * 4);
        s += (v.x + v.y) + (v.z + v.w);
    }
    #pragma unroll
    for (int d = 32; d >= 1; d >>= 1) s += __shfl_xor(s, d);
    __shared__ float ws[4];
    if ((tid & 63) == 0) ws[tid >> 6] = s;
    __syncthreads();
    if (tid == 0) out[0] = (ws[0] + ws[1] + ws[2] + ws[3]) * (1.0f / (Bb * Mm));
}

extern "C" void kernel_launch(void* const* d_in, const int* in_sizes, int n_in,
                              void* d_out, int out_size, void* d_ws, size_t ws_size,
                              hipStream_t stream) {
    const float* context   = (const float*)d_in[0];
    const float* positive  = (const float*)d_in[1];
    const float* negatives = (const float*)d_in[2];
    const void*  mask      = d_in[3];
    // d_in[4] = num_masked (512) — hardcoded as Mm.

    float* lossbuf = (float*)d_ws;    // 16 KB

    cl_main<<<GRID, 256, 0, stream>>>(context, positive, negatives, mask, lossbuf);
    cl_reduce<<<1, 256, 0, stream>>>(lossbuf, (float*)d_out);
}